// Round 4
// baseline (305.191 us; speedup 1.0000x reference)
//
#include <hip/hip_runtime.h>
#include <cstdint>

// ---------------------------------------------------------------------------
// AttentionSelector: selected = softmax(query @ (x@Wk^T+bk)^T) @ x
// R4: occupancy attack. R3 evidence: grid=512 = exactly 2 blocks/CU (hard cap),
//     ~5600 of ~7000 cyc/iter is barrier/latency stall that dbuf can't hide
//     with only 8 waves/CU. Changes:
//     (a) qb=64 (128 q/block, 4 waves x 32 q) -> grid 1024 = 4 blocks/CU.
//     (b) 32-pair tiles, dbuf 2x12KB = 24.6KB LDS (allows 4+ blocks/CU);
//         __launch_bounds__(256,4) pins VGPR<=128 for 16 waves/CU.
//     (c) prepB folded into prepA launch (one fewer dispatch).
// ---------------------------------------------------------------------------

typedef __bf16    bf16x4 __attribute__((ext_vector_type(4)));
typedef __bf16    bf16x8 __attribute__((ext_vector_type(8)));
typedef _Float16  f16x4  __attribute__((ext_vector_type(4)));
typedef _Float16  f16x8  __attribute__((ext_vector_type(8)));
typedef float     f32x16 __attribute__((ext_vector_type(16)));

extern "C" __device__ float __ocml_native_exp2_f32(float);

#define NUM_PAIRS   65536
#define NUM_Q       8192
#define DIM         66
#define KPITCH      84      // Kh row pitch (f16): 168B rows, 2-way-free reads
#define QPITCH      80      // Qh row pitch (f16)
#define XROWS       96      // xT rows: 0..65 data, 66 ones, 67..95 zero
#define XPITCH      36      // xT tile col pitch (72B rows, 2-way free)
#define XTILE       (XROWS*XPITCH)   // 3456 elems / 6912 B per 32-pair block
#define PARTP       68      // partial row pitch (floats)

// staged 32-pair tile (bytes): Kt [32][84] f16 = 5376 @0 ; Xt [96][36] bf16 = 6912 @5376
#define LDS_XT 5376
#define STG     12288       // 12 x 1KB chunks per tile
#define KSTRIDE 5376        // bytes of Kh per 32-pair tile
#define XSTRIDE 6912        // bytes of Xb per 32-pair tile

__device__ __forceinline__ bf16x8 frag8(const __bf16* p) {
    bf16x4 lo = *(const bf16x4*)p;
    bf16x4 hi = *(const bf16x4*)(p + 4);
    return __builtin_shufflevector(lo, hi, 0, 1, 2, 3, 4, 5, 6, 7);
}
__device__ __forceinline__ f16x8 frag8h(const _Float16* p) {
    f16x4 lo = *(const f16x4*)p;
    f16x4 hi = *(const f16x4*)(p + 4);
    return __builtin_shufflevector(lo, hi, 0, 1, 2, 3, 4, 5, 6, 7);
}
__device__ __forceinline__ f32x16 mfma_bf16(bf16x8 a, bf16x8 b, f32x16 c) {
    return __builtin_amdgcn_mfma_f32_32x32x16_bf16(a, b, c, 0, 0, 0);
}
__device__ __forceinline__ f32x16 mfma_f16(f16x8 a, f16x8 b, f32x16 c) {
    return __builtin_amdgcn_mfma_f32_32x32x16_f16(a, b, c, 0, 0, 0);
}

// gfx950: exchange lanes 32..63 of a with lanes 0..31 of b.
__device__ __forceinline__ void plswap(unsigned &a, unsigned &b) {
    asm("v_permlane32_swap_b32 %0, %1" : "+v"(a), "+v"(b));
}
__device__ __forceinline__ unsigned packbf(float a, float b) {
    union { __bf16 h[2]; unsigned u; } t;
    t.h[0] = (__bf16)a; t.h[1] = (__bf16)b;
    return t.u;
}

union U4 { unsigned u[4]; bf16x8 v; };

// Sᵀ C-tile (col=query l31, row(pair)=(r&3)+8*(r>>2)+4h) -> exp2 -> two PV
// A-frags (par0: pairs 0..15, par1: 16..31) via permlane32_swap (verified R2).
__device__ __forceinline__ void makefrags(const f32x16 &s, U4 *f) {
    float P[16];
    #pragma unroll
    for (int r = 0; r < 16; ++r) P[r] = __ocml_native_exp2_f32(s[r]);
    unsigned E0 = packbf(P[0],  P[1]),  E1 = packbf(P[2],  P[3]);
    unsigned F0 = packbf(P[4],  P[5]),  F1 = packbf(P[6],  P[7]);
    plswap(E0, F0); plswap(E1, F1);
    f[0].u[0] = E0; f[0].u[1] = E1; f[0].u[2] = F0; f[0].u[3] = F1;
    unsigned G0 = packbf(P[8],  P[9]),  G1 = packbf(P[10], P[11]);
    unsigned H0 = packbf(P[12], P[13]), H1 = packbf(P[14], P[15]);
    plswap(G0, H0); plswap(G1, H1);
    f[1].u[0] = G0; f[1].u[1] = G1; f[1].u[2] = H0; f[1].u[3] = H1;
}

__device__ __forceinline__ void stage_tile(char* dst, const char* gK, const char* gX,
                                           int wave, int lane) {
    #pragma unroll
    for (int j = 0; j < 3; ++j) {
        int c = wave + 4 * j;
        int off = c * 1024 + lane * 16;
        const char* src = (off < KSTRIDE) ? (gK + off) : (gX + (off - KSTRIDE));
        __builtin_amdgcn_global_load_lds(
            (const __attribute__((address_space(1))) void*)(uintptr_t)src,
            (__attribute__((address_space(3))) void*)(unsigned int)(uintptr_t)(dst + c * 1024),
            16, 0, 0);
    }
}

__device__ __forceinline__ void compute_tile(const char* sm, const f16x8 (&aQ)[5],
                                             f32x16 (&o)[3], int l31, int h) {
    const _Float16* Kt = (const _Float16*)sm;
    const __bf16*   Xt = (const __bf16*)(sm + LDS_XT);
    f16x8 bK[5];
    #pragma unroll
    for (int kk = 0; kk < 5; ++kk)
        bK[kk] = frag8h(&Kt[l31 * KPITCH + kk * 16 + h * 8]);
    f32x16 s = {};
    #pragma unroll
    for (int kk = 0; kk < 5; ++kk) s = mfma_f16(bK[kk], aQ[kk], s);
    U4 f[2];
    makefrags(s, f);
    #pragma unroll
    for (int par = 0; par < 2; ++par) {
        const int kc = par * 16 + h * 8;
        #pragma unroll
        for (int dt = 0; dt < 3; ++dt) {
            bf16x8 bX = frag8(&Xt[(dt * 32 + l31) * XPITCH + kc]);
            o[dt] = mfma_bf16(f[par].v, bX, o[dt]);
        }
    }
}

// ---------------------------------------------------------------------------
// Fused prep: blocks 0..511 = prepA (mfma f16 K-proj + X transpose);
//             blocks 512..1023 = prepB (Qh = query*log2e, f16, padded).
// ---------------------------------------------------------------------------
#define PA_ROWS 128
#define PAP 104
__global__ __launch_bounds__(256) void prep_kernel(
    const float* __restrict__ x, const float* __restrict__ query,
    const float* __restrict__ Wk, const float* __restrict__ bk,
    unsigned short* __restrict__ Kh_u, unsigned short* __restrict__ Xb_u,
    unsigned short* __restrict__ Qh_u) {
    const int tid = threadIdx.x;
    if (blockIdx.x >= 512) {
        _Float16* Qh = (_Float16*)Qh_u;
        int base = (blockIdx.x - 512) * 1280;      // 8192*80/512
        #pragma unroll
        for (int k = 0; k < 5; ++k) {
            int idx = base + k * 256 + tid;
            int q = idx / QPITCH, c = idx % QPITCH;
            float v = (c < DIM) ? query[(long)q * DIM + c] * 1.4426950408889634f : 0.f;
            Qh[idx] = (_Float16)v;
        }
        return;
    }
    _Float16* Kh = (_Float16*)Kh_u;
    __bf16*   Xb = (__bf16*)Xb_u;
    __shared__ _Float16 sxh[PA_ROWS * PAP];
    __shared__ _Float16 sW[96 * PAP];
    const long n0 = (long)blockIdx.x * PA_ROWS;

    for (int i = tid; i < PA_ROWS * 96; i += 256) {
        int r = i / 96, c = i % 96;
        sxh[r * PAP + c] = (_Float16)((c < DIM) ? x[(n0 + r) * DIM + c] : 0.f);
    }
    for (int i = tid; i < 96 * 96; i += 256) {
        int cc = i / 96, d = i % 96;
        sW[cc * PAP + d] = (_Float16)((cc < DIM && d < DIM) ? Wk[cc * DIM + d] : 0.f);
    }
    __syncthreads();

    const int lane = tid & 63, w = tid >> 6;
    const int l31 = lane & 31, h = lane >> 5;

    #pragma unroll
    for (int nt = 0; nt < 3; ++nt) {
        f32x16 acc = {};
        #pragma unroll
        for (int kk = 0; kk < 6; ++kk) {
            f16x8 a = *(const f16x8*)&sxh[(w * 32 + l31) * PAP + kk * 16 + h * 8];
            f16x8 b = *(const f16x8*)&sW[(nt * 32 + l31) * PAP + kk * 16 + h * 8];
            acc = mfma_f16(a, b, acc);
        }
        int c = nt * 32 + l31;
        float bkv = (c < DIM) ? bk[c] : 0.f;
        if (c < KPITCH) {
            #pragma unroll
            for (int r = 0; r < 16; ++r) {
                int row = (r & 3) + 8 * (r >> 2) + 4 * h;
                Kh[(n0 + w * 32 + row) * KPITCH + c] = (_Float16)(acc[r] + bkv);
            }
        }
    }

    for (int ii = tid; ii < 4 * XTILE; ii += 256) {
        int b = ii / XTILE, i = ii % XTILE;
        int dd = i / XPITCH, j = i % XPITCH;
        float v = 0.f;
        if (j < 32) {
            if (dd < DIM) v = (float)sxh[(b * 32 + j) * PAP + dd];
            else if (dd == DIM) v = 1.f;
        }
        Xb[((long)blockIdx.x * 4 + b) * XTILE + i] = (__bf16)v;
    }
}

// ---------------------------------------------------------------------------
// Flash: grid = 64 qblocks * NS chunks = 1024 blocks (4/CU); 4 waves x 32 q.
// 32-pair tiles, double-buffered; Sᵀ=K·Qᵀ f16 mfma, exp2 in-reg,
// permlane swap -> PV bf16 mfma. Partials to Part.
// ---------------------------------------------------------------------------
__global__ __launch_bounds__(256, 4) void flash_kernel(
    const unsigned short* __restrict__ Qh_u, const unsigned short* __restrict__ Kh_u,
    const unsigned short* __restrict__ Xb_u, float* __restrict__ Part, int NS) {
    __shared__ __attribute__((aligned(16))) char smA[STG];
    __shared__ __attribute__((aligned(16))) char smB[STG];
    const _Float16* Qh = (const _Float16*)Qh_u;

    const int tid = threadIdx.x;
    const int lane = tid & 63, wave = tid >> 6;
    const int l31 = lane & 31, h = lane >> 5;
    const int qb = blockIdx.x / NS, ns = blockIdx.x % NS;
    const int ppc = NUM_PAIRS / NS;
    const int iters = ppc >> 5;              // 32-pair tiles; even for NS<=16
    const int qbase = qb * 128 + wave * 32;

    const long pbase = (long)ns * ppc;
    const char* gK0 = (const char*)Kh_u + pbase * (KPITCH * 2);
    const char* gX0 = (const char*)Xb_u + (pbase >> 5) * (XTILE * 2);

    f16x8 aQ[5];
    #pragma unroll
    for (int kk = 0; kk < 5; ++kk)
        aQ[kk] = *(const f16x8*)&Qh[(long)(qbase + l31) * QPITCH + kk * 16 + h * 8];

    f32x16 o[3] = {};

    stage_tile(smA, gK0, gX0, wave, lane);
    for (int it = 0; it < iters; it += 2) {
        __syncthreads();   // tile it ready in A; everyone done reading B
        if (it + 1 < iters)
            stage_tile(smB, gK0 + (long)(it + 1) * KSTRIDE,
                            gX0 + (long)(it + 1) * XSTRIDE, wave, lane);
        compute_tile(smA, aQ, o, l31, h);
        __syncthreads();   // tile it+1 ready in B; everyone done reading A
        if (it + 2 < iters)
            stage_tile(smA, gK0 + (long)(it + 2) * KSTRIDE,
                            gX0 + (long)(it + 2) * XSTRIDE, wave, lane);
        compute_tile(smB, aQ, o, l31, h);
    }

    // epilogue: unnormalized partials; col 66 = sum(exp) denominator
    float* dst = Part + (long)ns * NUM_Q * PARTP;
    #pragma unroll
    for (int dt = 0; dt < 3; ++dt)
        #pragma unroll
        for (int r = 0; r < 16; ++r) {
            int row = (r & 3) + 8 * (r >> 2) + 4 * h;
            int q = qbase + row;
            int d = dt * 32 + l31;
            if (d < DIM + 1) dst[(long)q * PARTP + d] = o[dt][r];
        }
}

// ---------------------------------------------------------------------------
// Combine: out[q][d] = sum_ns Part[ns][q][d] / sum_ns Part[ns][q][66]
// ---------------------------------------------------------------------------
__global__ __launch_bounds__(256) void combine_kernel(
    const float* __restrict__ Part, float* __restrict__ out, int NS) {
    int q = blockIdx.x * 2 + (threadIdx.x >> 7);
    int d = threadIdx.x & 127;
    if (d >= DIM) return;
    float num = 0.f, den = 0.f;
    #pragma unroll 4
    for (int s = 0; s < NS; ++s) {
        const float* p = Part + ((long)s * NUM_Q + q) * PARTP;
        num += p[d];
        den += p[DIM];
    }
    out[(long)q * DIM + d] = num / den;
}

// ---------------------------------------------------------------------------
// Workspace: Qh @0 (1,310,720 B) ; Kh @1310720 (11,010,048 B) ;
//            Xb @12320768 (14,155,776 B) ; Part @26476544 (NS*8192*68*4 B)
// ---------------------------------------------------------------------------
extern "C" void kernel_launch(void* const* d_in, const int* in_sizes, int n_in,
                              void* d_out, int out_size, void* d_ws, size_t ws_size,
                              hipStream_t stream) {
    const float* x     = (const float*)d_in[0];
    const float* query = (const float*)d_in[1];
    const float* Wk    = (const float*)d_in[2];
    const float* bk    = (const float*)d_in[3];
    float* out = (float*)d_out;
    char* ws = (char*)d_ws;

    unsigned short* Qh = (unsigned short*)(ws + 0);
    unsigned short* Kh = (unsigned short*)(ws + 1310720);
    unsigned short* Xb = (unsigned short*)(ws + 12320768);
    float* Part        = (float*)(ws + 26476544);

    int NS = 16;
    while (NS > 1 &&
           26476544ULL + (unsigned long long)NS * NUM_Q * PARTP * 4ULL > (unsigned long long)ws_size)
        NS >>= 1;

    prep_kernel<<<1024, 256, 0, stream>>>(x, query, Wk, bk, Kh, Xb, Qh);
    flash_kernel<<<(NUM_Q / 128) * NS, 256, 0, stream>>>(Qh, Kh, Xb, Part, NS);
    combine_kernel<<<NUM_Q / 2, 256, 0, stream>>>(Part, out, NS);
}

// Round 5
// 280.098 us; speedup vs baseline: 1.0896x; 1.0896x over previous
//
#include <hip/hip_runtime.h>
#include <cstdint>

// ---------------------------------------------------------------------------
// AttentionSelector: selected = softmax(query @ (x@Wk^T+bk)^T) @ x
// R5: barrier-free flash. R4 evidence: occupancy 2x -> no gain; the 2-barrier
//     LDS K-loop's per-iter drain+DMA latency (~400cyc/iter) is structural
//     (m97 plateau). New structure:
//     - prep emits K/X as MFMA-FRAGMENT STREAMS (per 32-pair tile: 5x1KB f16
//       K-frags + 6x1KB bf16 X-frags, lane-contiguous dwordx4 loads).
//     - flash: no LDS, no __syncthreads. Frags load global->VGPR; 4 waves of
//       a block read identical addresses (L1 dedupe); compiler pipelines with
//       fine vmcnt. K double-buffered in regs; X issued at compute top.
//     - qt=2 (64q/wave): 22 mfma per 11 loads.
//     - Part laid out [q][NS][68] so combine reads contiguously.
// ---------------------------------------------------------------------------

typedef __bf16    bf16x4 __attribute__((ext_vector_type(4)));
typedef __bf16    bf16x8 __attribute__((ext_vector_type(8)));
typedef _Float16  f16x4  __attribute__((ext_vector_type(4)));
typedef _Float16  f16x8  __attribute__((ext_vector_type(8)));
typedef float     f32x16 __attribute__((ext_vector_type(16)));

extern "C" __device__ float __ocml_native_exp2_f32(float);

#define NUM_PAIRS   65536
#define NUM_Q       8192
#define DIM         66
#define QPITCH      80        // Qh row pitch (f16)
#define KFT         2560      // Kf f16 per 32-pair tile (5 kk x 512)
#define XFT         3072      // Xf bf16 per 32-pair tile (6 c x 512)
#define PARTP       68        // partial row pitch (floats)
#define NTILES      (NUM_PAIRS/32)   // 2048

__device__ __forceinline__ f32x16 mfma_bf16(bf16x8 a, bf16x8 b, f32x16 c) {
    return __builtin_amdgcn_mfma_f32_32x32x16_bf16(a, b, c, 0, 0, 0);
}
__device__ __forceinline__ f32x16 mfma_f16(f16x8 a, f16x8 b, f32x16 c) {
    return __builtin_amdgcn_mfma_f32_32x32x16_f16(a, b, c, 0, 0, 0);
}
// gfx950: exchange lanes 32..63 of a with lanes 0..31 of b.
__device__ __forceinline__ void plswap(unsigned &a, unsigned &b) {
    asm("v_permlane32_swap_b32 %0, %1" : "+v"(a), "+v"(b));
}
__device__ __forceinline__ unsigned packbf(float a, float b) {
    union { __bf16 h[2]; unsigned u; } t;
    t.h[0] = (__bf16)a; t.h[1] = (__bf16)b;
    return t.u;
}
union U4 { unsigned u[4]; bf16x8 v; };

// Sᵀ C-tile (col=query l31, row(pair)=(r&3)+8*(r>>2)+4h) -> exp2 -> two PV
// A-frags (par0: pairs 0..15, par1: 16..31) via permlane32_swap (verified R2-R4).
__device__ __forceinline__ void makefrags(const f32x16 &s, U4 *f) {
    float P[16];
    #pragma unroll
    for (int r = 0; r < 16; ++r) P[r] = __ocml_native_exp2_f32(s[r]);
    unsigned E0 = packbf(P[0],  P[1]),  E1 = packbf(P[2],  P[3]);
    unsigned F0 = packbf(P[4],  P[5]),  F1 = packbf(P[6],  P[7]);
    plswap(E0, F0); plswap(E1, F1);
    f[0].u[0] = E0; f[0].u[1] = E1; f[0].u[2] = F0; f[0].u[3] = F1;
    unsigned G0 = packbf(P[8],  P[9]),  G1 = packbf(P[10], P[11]);
    unsigned H0 = packbf(P[12], P[13]), H1 = packbf(P[14], P[15]);
    plswap(G0, H0); plswap(G1, H1);
    f[1].u[0] = G0; f[1].u[1] = G1; f[1].u[2] = H0; f[1].u[3] = H1;
}

__device__ __forceinline__ void compute_tile(const f16x8 (&kc)[5], const __bf16* __restrict__ xp,
                                             const f16x8 (&aQ)[2][5], f32x16 (&o)[2][3]) {
    bf16x8 xa[6];
    #pragma unroll
    for (int c = 0; c < 6; ++c) xa[c] = *(const bf16x8*)(xp + c * 512);
    f32x16 s0 = {}, s1 = {};
    #pragma unroll
    for (int kk = 0; kk < 5; ++kk) {
        s0 = mfma_f16(kc[kk], aQ[0][kk], s0);
        s1 = mfma_f16(kc[kk], aQ[1][kk], s1);
    }
    U4 f0[2], f1[2];
    makefrags(s0, f0);
    makefrags(s1, f1);
    #pragma unroll
    for (int par = 0; par < 2; ++par)
        #pragma unroll
        for (int dt = 0; dt < 3; ++dt) {
            o[0][dt] = mfma_bf16(f0[par].v, xa[par * 3 + dt], o[0][dt]);
            o[1][dt] = mfma_bf16(f1[par].v, xa[par * 3 + dt], o[1][dt]);
        }
}

// ---------------------------------------------------------------------------
// Prep: blocks 0..511 -> 128 pairs each: K = x@Wk^T+bk (mfma f16), emit Kf
//       fragment stream + Xf fragment stream. Blocks 512..1023 -> Qh.
// ---------------------------------------------------------------------------
#define PAP 104   // sxh/sW pitch (f16)
#define SKP 88    // sK pitch (f16)
__global__ __launch_bounds__(256) void prep_kernel(
    const float* __restrict__ x, const float* __restrict__ query,
    const float* __restrict__ Wk, const float* __restrict__ bk,
    unsigned short* __restrict__ Kf_u, unsigned short* __restrict__ Xf_u,
    unsigned short* __restrict__ Qh_u) {
    const int tid = threadIdx.x;
    if (blockIdx.x >= 512) {
        _Float16* Qh = (_Float16*)Qh_u;
        int base = (blockIdx.x - 512) * 1280;      // 8192*80/512
        #pragma unroll
        for (int k = 0; k < 5; ++k) {
            int idx = base + k * 256 + tid;
            int q = idx / QPITCH, c = idx % QPITCH;
            float v = (c < DIM) ? query[(long)q * DIM + c] * 1.4426950408889634f : 0.f;
            Qh[idx] = (_Float16)v;
        }
        return;
    }
    _Float16* Kf = (_Float16*)Kf_u;
    __bf16*   Xf = (__bf16*)Xf_u;
    __shared__ _Float16 sxh[128 * PAP];   // x rows (f16), k-padded
    __shared__ _Float16 sW[96 * PAP];     // Wk rows (f16), padded
    __shared__ _Float16 sK[128 * SKP];    // K results [pair][feature]
    const long n0 = (long)blockIdx.x * 128;

    for (int i = tid; i < 128 * 96; i += 256) {
        int r = i / 96, c = i % 96;
        sxh[r * PAP + c] = (_Float16)((c < DIM) ? x[(n0 + r) * DIM + c] : 0.f);
    }
    for (int i = tid; i < 96 * 96; i += 256) {
        int cc = i / 96, d = i % 96;
        sW[cc * PAP + d] = (_Float16)((cc < DIM && d < DIM) ? Wk[cc * DIM + d] : 0.f);
    }
    __syncthreads();

    const int lane = tid & 63, w = tid >> 6;
    const int l31 = lane & 31, h = lane >> 5;

    #pragma unroll
    for (int nt = 0; nt < 3; ++nt) {
        f32x16 acc = {};
        #pragma unroll
        for (int kk = 0; kk < 6; ++kk) {
            f16x8 a = *(const f16x8*)&sxh[(w * 32 + l31) * PAP + kk * 16 + h * 8];
            f16x8 b = *(const f16x8*)&sW[(nt * 32 + l31) * PAP + kk * 16 + h * 8];
            acc = mfma_f16(a, b, acc);
        }
        int c = nt * 32 + l31;
        float bkv = (c < DIM) ? bk[c] : 0.f;
        if (c < SKP) {
            #pragma unroll
            for (int r = 0; r < 16; ++r) {
                int row = (r & 3) + 8 * (r >> 2) + 4 * h;
                sK[(w * 32 + row) * SKP + c] = (_Float16)(acc[r] + bkv);
            }
        }
    }
    __syncthreads();

    // Kf emission: [tile][kk][lane][8] ; 4 tiles x 5 kk x 64 lanes = 1280 slots
    for (int i = 0; i < 5; ++i) {
        int slot = i * 256 + tid;
        int tt = slot / 320, rem = slot % 320;
        int kk = rem / 64, l = rem % 64;
        const _Float16* src = &sK[(32 * tt + (l & 31)) * SKP + kk * 16 + (l >> 5) * 8];
        f16x4 lo = *(const f16x4*)src;
        f16x4 hi = *(const f16x4*)(src + 4);
        f16x8 v = __builtin_shufflevector(lo, hi, 0, 1, 2, 3, 4, 5, 6, 7);
        *(f16x8*)&Kf[((long)blockIdx.x * 4 + tt) * KFT + kk * 512 + l * 8] = v;
    }
    // Xf emission: [tile][c=par*3+dt][lane][8] ; content X^T[d][pair]
    for (int i = 0; i < 6; ++i) {
        int slot = i * 256 + tid;
        int tt = slot / 384, rem = slot % 384;
        int c = rem / 64, l = rem % 64;
        int dt = c % 3, par = c / 3;
        int d = 32 * dt + (l & 31);
        int p0 = 32 * tt + 16 * par + 8 * (l >> 5);
        bf16x8 v;
        #pragma unroll
        for (int j = 0; j < 8; ++j) {
            float vv = 0.f;
            if (d < DIM) vv = (float)sxh[(p0 + j) * PAP + d];
            else if (d == DIM) vv = 1.f;
            v[j] = (__bf16)vv;
        }
        *(bf16x8*)&Xf[((long)blockIdx.x * 4 + tt) * XFT + c * 512 + l * 8] = v;
    }
}

// ---------------------------------------------------------------------------
// Flash: grid = 32 qblocks * NS; 256 thr = 4 waves x 64 q (qt=2). No LDS, no
// __syncthreads. Per 32-pair tile: 11 coalesced dwordx4 frag loads, 22 mfma.
// K regs double-buffered; raw s_barrier every 32 tiles bounds wave drift.
// ---------------------------------------------------------------------------
__global__ __launch_bounds__(256, 2) void flash_kernel(
    const unsigned short* __restrict__ Qh_u, const unsigned short* __restrict__ Kf_u,
    const unsigned short* __restrict__ Xf_u, float* __restrict__ Part, int NS) {
    const _Float16* Qh = (const _Float16*)Qh_u;
    const _Float16* Kf = (const _Float16*)Kf_u;
    const __bf16*   Xf = (const __bf16*)Xf_u;

    const int tid = threadIdx.x;
    const int lane = tid & 63, wave = tid >> 6;
    const int l31 = lane & 31, h = lane >> 5;
    const int qb = blockIdx.x / NS, ns = blockIdx.x % NS;
    const int tiles = NTILES / NS;            // 128 at NS=16 (even)
    const int qbase = qb * 256 + wave * 64;

    const _Float16* kf = Kf + (long)(ns * tiles) * KFT + lane * 8;
    const __bf16*   xf = Xf + (long)(ns * tiles) * XFT + lane * 8;

    f16x8 aQ[2][5];
    #pragma unroll
    for (int qt = 0; qt < 2; ++qt)
        #pragma unroll
        for (int kk = 0; kk < 5; ++kk)
            aQ[qt][kk] = *(const f16x8*)&Qh[(long)(qbase + qt * 32 + l31) * QPITCH + kk * 16 + h * 8];

    f32x16 o[2][3] = {};

    f16x8 kA[5], kB[5];
    #pragma unroll
    for (int kk = 0; kk < 5; ++kk) kA[kk] = *(const f16x8*)(kf + kk * 512);

    for (int t = 0; t < tiles; t += 2) {
        if ((t & 31) == 0) asm volatile("s_barrier");   // drift bound, no drain
        {   // prefetch K(t+1)
            const _Float16* kp = kf + (long)(t + 1) * KFT;
            #pragma unroll
            for (int kk = 0; kk < 5; ++kk) kB[kk] = *(const f16x8*)(kp + kk * 512);
        }
        compute_tile(kA, xf + (long)t * XFT, aQ, o);
        if (t + 2 < tiles) {   // prefetch K(t+2)
            const _Float16* kp = kf + (long)(t + 2) * KFT;
            #pragma unroll
            for (int kk = 0; kk < 5; ++kk) kA[kk] = *(const f16x8*)(kp + kk * 512);
        }
        compute_tile(kB, xf + (long)(t + 1) * XFT, aQ, o);
    }

    // epilogue: unnormalized partials, layout [q][NS][68]; col 66 = denom
    #pragma unroll
    for (int qt = 0; qt < 2; ++qt)
        #pragma unroll
        for (int dt = 0; dt < 3; ++dt)
            #pragma unroll
            for (int r = 0; r < 16; ++r) {
                int row = (r & 3) + 8 * (r >> 2) + 4 * h;
                int q = qbase + qt * 32 + row;
                int d = dt * 32 + l31;
                if (d < DIM + 1)
                    Part[((long)q * NS + ns) * PARTP + d] = o[qt][dt][r];
            }
}

// ---------------------------------------------------------------------------
// Combine: out[q][d] = sum_s Part[q][s][d] / sum_s Part[q][s][66]
// Part rows for one q are contiguous (NS*272 B).
// ---------------------------------------------------------------------------
__global__ __launch_bounds__(256) void combine_kernel(
    const float* __restrict__ Part, float* __restrict__ out, int NS) {
    int q = blockIdx.x * 2 + (threadIdx.x >> 7);
    int d = threadIdx.x & 127;
    if (d >= DIM) return;
    const float* base = Part + (long)q * NS * PARTP;
    float num = 0.f, den = 0.f;
    #pragma unroll 4
    for (int s = 0; s < NS; ++s) {
        num += base[s * PARTP + d];
        den += base[s * PARTP + DIM];
    }
    out[(long)q * DIM + d] = num / den;
}

// ---------------------------------------------------------------------------
// Workspace: Qh @0 (1,310,720 B) ; Kf @1,310,720 (10,485,760 B) ;
//            Xf @11,796,480 (12,582,912 B) ; Part @24,379,392 (8192*NS*68*4)
// ---------------------------------------------------------------------------
extern "C" void kernel_launch(void* const* d_in, const int* in_sizes, int n_in,
                              void* d_out, int out_size, void* d_ws, size_t ws_size,
                              hipStream_t stream) {
    const float* x     = (const float*)d_in[0];
    const float* query = (const float*)d_in[1];
    const float* Wk    = (const float*)d_in[2];
    const float* bk    = (const float*)d_in[3];
    float* out = (float*)d_out;
    char* ws = (char*)d_ws;

    unsigned short* Qh = (unsigned short*)(ws + 0);
    unsigned short* Kf = (unsigned short*)(ws + 1310720);
    unsigned short* Xf = (unsigned short*)(ws + 11796480);
    float* Part        = (float*)(ws + 24379392);

    int NS = 16;
    while (NS > 1 &&
           24379392ULL + (unsigned long long)NS * NUM_Q * PARTP * 4ULL > (unsigned long long)ws_size)
        NS >>= 1;

    prep_kernel<<<1024, 256, 0, stream>>>(x, query, Wk, bk, Kf, Xf, Qh);
    flash_kernel<<<(NUM_Q / 256) * NS, 256, 0, stream>>>(Qh, Kf, Xf, Part, NS);
    combine_kernel<<<NUM_Q / 2, 256, 0, stream>>>(Part, out, NS);
}